// Round 9
// baseline (946.917 us; speedup 1.0000x reference)
//
#include <hip/hip_runtime.h>
#include <hip/hip_bf16.h>

// Problem constants (B, N, C fixed by reference)
#define BB 8
#define NN 2048
#define CC 256
#define GG 64        // C / NGRP groups of 4 channels
#define QQ 8

typedef unsigned short u16;
typedef __attribute__((ext_vector_type(8))) short bf16x8;   // 8 bf16 (4 VGPRs)
typedef __attribute__((ext_vector_type(4))) float f32x4;    // MFMA accumulator

static __device__ __forceinline__ float b2f(u16 u) {
  union { unsigned int i; float f; } cv; cv.i = ((unsigned int)u) << 16; return cv.f;
}
static __device__ __forceinline__ u16 f2b(float f) {
  union { __hip_bfloat16 h; u16 u; } cv; cv.h = __float2bfloat16(f); return cv.u;
}
// dtype-flexible scalar load: flag ? float32 : bf16
static __device__ __forceinline__ float ldin(const void* p, size_t i, bool f32) {
  return f32 ? ((const float*)p)[i] : b2f(((const u16*)p)[i]);
}
// 4 consecutive elements as float4 (dtype-flexible)
static __device__ __forceinline__ float4 ldin4(const void* p, size_t i, bool f32) {
  if (f32) return *(const float4*)((const float*)p + i);
  ushort4 u = *(const ushort4*)((const u16*)p + i);
  return make_float4(b2f(u.x), b2f(u.y), b2f(u.z), b2f(u.w));
}
// async global->LDS, 16B per lane; LDS dest = wave-uniform base + lane*16
static __device__ __forceinline__ void gload16(const void* g, void* l) {
  __builtin_amdgcn_global_load_lds(
      (const __attribute__((address_space(1))) void*)g,
      (__attribute__((address_space(3))) void*)l, 16, 0, 0);
}

// ---------------------------------------------------------------------------
// dtype detection (bf16 vs f32 inputs)
// ---------------------------------------------------------------------------
__global__ __launch_bounds__(256) void detect_kernel(const u16* __restrict__ sc,
                                                     int* __restrict__ flag)
{
  __shared__ int sh;
  if (threadIdx.x == 0) sh = 0;
  __syncthreads();
  int cnt = 0;
  for (int i = threadIdx.x; i < 2048; i += 256) {
    u16 w = sc[2 * i];
    int e = (w >> 7) & 0xFF;
    if (e >= 100 && e <= 130) cnt++;
  }
  atomicAdd(&sh, cnt);
  __syncthreads();
  if (threadIdx.x == 0) *flag = (sh < 1024) ? 1 : 0;   // 1 => float32 inputs
}

// ---------------------------------------------------------------------------
// K[bl,i,j] = 0.5*(sc[b,i,j]+sc[b,j,i]) * sigmoid(dot(U[i],U[j]))
// Batch-parallel (r8 win): grid (64,64,nbat), z = batch; sigmoid recomputed
// per batch (VALU idle anyway) for 8x memory-level parallelism.
// ---------------------------------------------------------------------------
__global__ __launch_bounds__(256) void build_k_kernel(
    const void* __restrict__ sc, const void* __restrict__ U,
    u16* __restrict__ Khi, u16* __restrict__ Klo,
    const int* __restrict__ flagp, int b0)
{
  const int i0 = blockIdx.y * 32;
  const int j0 = blockIdx.x * 32;
  if (j0 < i0) return;
  const bool f32 = (*flagp != 0);
  const int bl = blockIdx.z;
  const int b  = b0 + bl;
  const int tx = threadIdx.x;   // 0..31
  const int ty = threadIdx.y;   // 0..7
  const int t  = ty * 32 + tx;
  const int rr = t >> 3;        // row 0..31
  const int cq = t & 7;         // col quad 0..7 (cols 4cq..4cq+3)

  __shared__ float Ui[32][17];
  __shared__ float Uj[32][17];
  __shared__ float As[32][33];   // As[a][c] = sigmoid(dot(U[i0+a], U[j0+c]))
  __shared__ float t1[32][33];   // t1[a][c] = sc[b, i0+a, j0+c]
  __shared__ float t2[32][33];   // t2[a][c] = sc[b, j0+a, i0+c]

  for (int s = t; s < 512; s += 256) {
    int r2 = s >> 4, kk = s & 15;
    Ui[r2][kk] = ldin(U, (size_t)(i0 + r2) * 16 + kk, f32);
    Uj[r2][kk] = ldin(U, (size_t)(j0 + r2) * 16 + kk, f32);
  }
  const size_t scb = (size_t)b * NN * NN;
  float4 va = ldin4(sc, scb + (size_t)(i0 + rr) * NN + j0 + 4 * cq, f32);
  float4 vb = ldin4(sc, scb + (size_t)(j0 + rr) * NN + i0 + 4 * cq, f32);
  __syncthreads();
  for (int ii = ty; ii < 32; ii += 8) {
    float dot = 0.f;
    #pragma unroll
    for (int k = 0; k < 16; k++) dot += Ui[ii][k] * Uj[tx][k];
    As[ii][tx] = 1.0f / (1.0f + expf(-dot));
  }
  t1[rr][4*cq+0] = va.x; t1[rr][4*cq+1] = va.y;
  t1[rr][4*cq+2] = va.z; t1[rr][4*cq+3] = va.w;
  t2[rr][4*cq+0] = vb.x; t2[rr][4*cq+1] = vb.y;
  t2[rr][4*cq+2] = vb.z; t2[rr][4*cq+3] = vb.w;
  __syncthreads();

  const size_t kfb = (size_t)bl * NN * NN;
  ushort4 h4, l4;
  #pragma unroll
  for (int k = 0; k < 4; k++) {
    int col = 4 * cq + k;
    float kv = 0.5f * (t1[rr][col] + t2[col][rr]) * As[rr][col];
    u16 h = f2b(kv);
    ((u16*)&h4)[k] = h;
    ((u16*)&l4)[k] = f2b(kv - b2f(h));
  }
  size_t o = kfb + (size_t)(i0 + rr) * NN + j0 + 4 * cq;
  *(ushort4*)(Khi + o) = h4;
  *(ushort4*)(Klo + o) = l4;
  if (i0 != j0) {
    #pragma unroll
    for (int k = 0; k < 4; k++) {
      int col = 4 * cq + k;
      float kv = 0.5f * (t2[rr][col] + t1[col][rr]) * As[col][rr];
      u16 h = f2b(kv);
      ((u16*)&h4)[k] = h;
      ((u16*)&l4)[k] = f2b(kv - b2f(h));
    }
    size_t o2 = kfb + (size_t)(j0 + rr) * NN + i0 + 4 * cq;
    *(ushort4*)(Khi + o2) = h4;
    *(ushort4*)(Klo + o2) = l4;
  }
}

// ---------------------------------------------------------------------------
// GroupNorm stats over y[b, 4g:4g+4, :]  (8192 elems per (b,g))
// ---------------------------------------------------------------------------
__global__ __launch_bounds__(256) void gn_stats_kernel(
    const void* __restrict__ y, float* __restrict__ murs,
    const int* __restrict__ flagp)
{
  const bool f32 = (*flagp != 0);
  const int bg = blockIdx.x;                    // b*64 + g
  float s = 0.f, ss = 0.f;
  if (f32) {
    const float* base = (const float*)y + (size_t)bg * 4 * NN;
    for (int i = threadIdx.x; i < 2048; i += 256) {
      float4 v = *(const float4*)(base + (size_t)i * 4);
      s  += v.x + v.y + v.z + v.w;
      ss += v.x*v.x + v.y*v.y + v.z*v.z + v.w*v.w;
    }
  } else {
    const u16* base = (const u16*)y + (size_t)bg * 4 * NN;
    for (int i = threadIdx.x; i < 2048; i += 256) {
      ushort4 v = *(const ushort4*)(base + (size_t)i * 4);
      float f0 = b2f(v.x), f1 = b2f(v.y), f2 = b2f(v.z), f3 = b2f(v.w);
      s  += f0 + f1 + f2 + f3;
      ss += f0*f0 + f1*f1 + f2*f2 + f3*f3;
    }
  }
  #pragma unroll
  for (int off = 32; off > 0; off >>= 1) {
    s  += __shfl_down(s, off, 64);
    ss += __shfl_down(ss, off, 64);
  }
  __shared__ float sh[8];
  const int w = threadIdx.x >> 6, ln = threadIdx.x & 63;
  if (ln == 0) { sh[w * 2] = s; sh[w * 2 + 1] = ss; }
  __syncthreads();
  if (threadIdx.x == 0) {
    float S  = sh[0] + sh[2] + sh[4] + sh[6];
    float SS = sh[1] + sh[3] + sh[5] + sh[7];
    float mu  = S / 8192.0f;
    float var = SS / 8192.0f - mu * mu;
    murs[bg * 2]     = mu;
    murs[bg * 2 + 1] = 1.0f / sqrtf(fmaxf(var, 0.f) + 1e-5f);
  }
}

// ---------------------------------------------------------------------------
// y_t[b,n,c] = sphere( GN(y)[b,c,n] * w + bias ) -> f32 [b][n][c]
// ---------------------------------------------------------------------------
__global__ __launch_bounds__(256) void y_tf_kernel(
    const void* __restrict__ y, const float* __restrict__ murs,
    const void* __restrict__ gw, const void* __restrict__ gb,
    float* __restrict__ yt, const int* __restrict__ flagp)
{
  const bool f32 = (*flagp != 0);
  const int b = blockIdx.y;
  const int n = blockIdx.x * 64 + threadIdx.x;
  for (int g = threadIdx.y; g < GG; g += 4) {
    float mu = murs[(b * GG + g) * 2];
    float rs = murs[(b * GG + g) * 2 + 1];
    float v[4];
    #pragma unroll
    for (int k = 0; k < 4; k++) {
      int c = 4 * g + k;
      float val = (ldin(y, ((size_t)b * CC + c) * NN + n, f32) - mu) * rs;
      v[k] = val * ldin(gw, c, f32) + ldin(gb, c, f32);
    }
    float n2 = v[0]*v[0] + v[1]*v[1] + v[2]*v[2] + v[3]*v[3];
    float scl = 1.0f / sqrtf(fmaxf(n2, 1e-6f));
    float4 o; o.x = v[0]*scl; o.y = v[1]*scl; o.z = v[2]*scl; o.w = v[3]*scl;
    *(float4*)(yt + ((size_t)b * NN + n) * CC + 4 * g) = o;
  }
}

// ---------------------------------------------------------------------------
// x init: sphere-normalize x -> bf16 hi/lo transposed state xT[b][c][n]
// ---------------------------------------------------------------------------
__global__ __launch_bounds__(256) void x_init_kernel(
    const void* __restrict__ x, u16* __restrict__ xTh, u16* __restrict__ xTl,
    const int* __restrict__ flagp)
{
  const bool f32 = (*flagp != 0);
  const int b = blockIdx.y;
  const int n = blockIdx.x * 64 + threadIdx.x;
  for (int g = threadIdx.y; g < GG; g += 4) {
    size_t idx = ((size_t)b * NN + n) * CC + 4 * g;
    float v[4];
    if (f32) {
      float4 u4 = *(const float4*)((const float*)x + idx);
      v[0] = u4.x; v[1] = u4.y; v[2] = u4.z; v[3] = u4.w;
    } else {
      ushort4 u = *(const ushort4*)((const u16*)x + idx);
      v[0] = b2f(u.x); v[1] = b2f(u.y); v[2] = b2f(u.z); v[3] = b2f(u.w);
    }
    float n2 = v[0]*v[0] + v[1]*v[1] + v[2]*v[2] + v[3]*v[3];
    float scl = 1.0f / sqrtf(fmaxf(n2, 1e-6f));
    size_t xb = ((size_t)b * CC + 4 * g) * NN + n;
    #pragma unroll
    for (int k = 0; k < 4; k++) {
      float xv = v[k] * scl;
      u16 h = f2b(xv);
      xTh[xb + (size_t)k * NN] = h;
      xTl[xb + (size_t)k * NN] = f2b(xv - b2f(h));
    }
  }
}

// ===========================================================================
// Shared fused-step epilogue. Rows: rb + fr*16 + lk*4 + r. Cols: cb + fc*16
// + l15. The 4-channel group spans lanes differing in l15 bits 0..1.
// ===========================================================================
template<int NFR, int NFC>
static __device__ __forceinline__ void fused_step_epilogue(
    f32x4 (&acc)[NFR][NFC], int b, int rb, int cb, int l15, int lk,
    const u16* __restrict__ xhc, const u16* __restrict__ xlc,
    u16* __restrict__ xhn, u16* __restrict__ xln,
    const float* __restrict__ yt, const void* __restrict__ omega,
    const void* __restrict__ gamma, void* __restrict__ outbase, size_t qoff,
    bool f32)
{
  const float gm = ldin(gamma, 0, f32);
  #pragma unroll
  for (int fr = 0; fr < NFR; fr++) {
    const int rbase = rb + fr * 16 + lk * 4;
    #pragma unroll
    for (int fc = 0; fc < NFC; fc++) {
      const int c = cb + fc * 16 + l15;
      const size_t xoff = ((size_t)b * CC + c) * NN + rbase;
      ushort4 xh4 = *(const ushort4*)(xhc + xoff);
      ushort4 xl4 = *(const ushort4*)(xlc + xoff);
      float xcv[4] = { b2f(xh4.x) + b2f(xl4.x), b2f(xh4.y) + b2f(xl4.y),
                       b2f(xh4.z) + b2f(xl4.z), b2f(xh4.w) + b2f(xl4.w) };
      float om   = fabsf(ldin(omega, c >> 1, f32));
      float omsg = (c & 1) ? -om : om;
      float xn[4];
      #pragma unroll
      for (int r = 0; r < 4; r++) {
        const int n = rbase + r;
        float f = acc[fr][fc][r] + yt[((size_t)b * NN + n) * CC + c];
        float s = xcv[r] * f;
        s += __shfl_xor(s, 1);
        s += __shfl_xor(s, 2);
        float xp = __shfl_xor(xcv[r], 1);       // pair partner channel c^1
        float d  = omsg * xp + (f - s * xcv[r]);
        float v  = xcv[r] + gm * d;
        float n2 = v * v;
        n2 += __shfl_xor(n2, 1);
        n2 += __shfl_xor(n2, 2);
        float scl = 1.0f / sqrtf(fmaxf(n2, 1e-6f));
        xn[r] = v * scl;
        const size_t oidx = qoff + ((size_t)b * NN + n) * CC + c;
        if (f32) __builtin_nontemporal_store(xn[r], (float*)outbase + oidx);
        else     __builtin_nontemporal_store(f2b(xn[r]), (u16*)outbase + oidx);
      }
      ushort4 nh, nl;
      #pragma unroll
      for (int r = 0; r < 4; r++) {
        u16 h = f2b(xn[r]);
        ((u16*)&nh)[r] = h;
        ((u16*)&nl)[r] = f2b(xn[r] - b2f(h));
      }
      *(ushort4*)(xhn + xoff) = nh;
      *(ushort4*)(xln + xoff) = nl;
    }
  }
}

// ---------------------------------------------------------------------------
// Round-9 gemm: r3's pure-HIP compiler-scheduled dbuf structure (the best
// measured per-byte efficiency of the session: 50 B/cyc effective LDS vs
// 32 B/cyc for every asm-fenced variant — m141: sched_barrier order-pinning
// defeats hipcc's own lgkmcnt interleave), applied at a lower-traffic tile:
//   BM=128, BN=64, BK=32, 4 waves (2x2), wave 64x32 (4x2 16x16 frags)
//   -> 288 MB/batch-q LDS traffic vs r3's 384 (A-dup halved).
// NO inline asm; plain __syncthreads dbuf; NO swizzle needed: with BK=32 the
// row stride is 64 B, so a wave's b128 fragment read maps (row&1, chunk) to
// 8 uniform bank-groups of 8 lanes — conflict-free on a linear layout.
// LDS: 2 x 24 KB. Grid (4,16,8) = 512 blocks, 2/CU; one batch per XCD.
// ---------------------------------------------------------------------------
__global__ __launch_bounds__(256, 2) void gemm_fused_r9(
    const u16* __restrict__ Khi, const u16* __restrict__ Klo,
    const u16* __restrict__ xhc, const u16* __restrict__ xlc,
    u16* __restrict__ xhn, u16* __restrict__ xln,
    const float* __restrict__ yt, const void* __restrict__ omega,
    const void* __restrict__ gamma, void* __restrict__ outbase, size_t qoff,
    const int* __restrict__ flagp)
{
  const int flat = blockIdx.x + 4 * blockIdx.y + 64 * blockIdx.z;  // 0..511
  const int swz  = (flat & 7) * 64 + (flat >> 3);   // bijective (512 % 8 == 0)
  const int bx = swz & 3;
  const int by = (swz >> 2) & 15;
  const int b  = swz >> 6;                          // batch 0..7 (= K slot)
  const int m0 = by * 128;
  const int c0 = bx * 64;

  // per buffer: Ah[128][32] @0 (8KB), Al @8192, Bh[64][32] @16384 (4KB), Bl @20480
  __shared__ char lds[2][24576];

  const int t    = threadIdx.x;
  const int lane = t & 63;
  const int wid  = t >> 6;      // 0..3
  const int wr   = wid >> 1;    // wave row 0..1 (64 rows each)
  const int wc   = wid & 1;     // wave col 0..1 (32 cols each)

  const u16* Ah = Khi + (size_t)b * NN * NN;
  const u16* Al = Klo + (size_t)b * NN * NN;
  const u16* Bh = xhc + (size_t)b * CC * NN;
  const u16* Bl = xlc + (size_t)b * CC * NN;

  // staging: rows have 64 B (4 chunks of 16 B). thread t covers row t>>2
  // (+64 for A's second round), chunk t&3. LDS dest linear = t*16 per round.
  const int tr   = t >> 2;                       // 0..63
  const int ck   = t & 3;
  const size_t aoff = (size_t)(m0 + tr) * NN + ck * 8;
  const size_t boff = (size_t)(c0 + tr) * NN + ck * 8;
  const int dst = wid * 1024;                    // + lane*16 implicit in HW

  f32x4 acc[4][2];
  const f32x4 zero4 = {0.f, 0.f, 0.f, 0.f};
  #pragma unroll
  for (int i = 0; i < 4; i++)
    #pragma unroll
    for (int j = 0; j < 2; j++) acc[i][j] = zero4;

  auto stage = [&](int bufi, int kt) {           // 6 vmem ops per thread
    char* base = &lds[bufi][0];
    const int k0 = kt * 32;
    gload16(Ah + aoff + k0,               base +         dst);
    gload16(Ah + aoff + (size_t)64 * NN + k0, base +  4096 + dst);
    gload16(Al + aoff + k0,               base +  8192 + dst);
    gload16(Al + aoff + (size_t)64 * NN + k0, base + 12288 + dst);
    gload16(Bh + boff + k0,               base + 16384 + dst);
    gload16(Bl + boff + k0,               base + 20480 + dst);
  };

  const int l15 = lane & 15;
  const int lk  = lane >> 4;     // 0..3 (16B k-chunk within the K=32 row)

  auto compute = [&](int bufi) {
    const char* base = &lds[bufi][0];
    bf16x8 fah[4], fal[4], fbh[2], fbl[2];
    #pragma unroll
    for (int fr = 0; fr < 4; fr++) {
      int off = (wr * 64 + fr * 16 + l15) * 64 + lk * 16;
      fah[fr] = *(const bf16x8*)(base + off);
      fal[fr] = *(const bf16x8*)(base + 8192 + off);
    }
    #pragma unroll
    for (int fc = 0; fc < 2; fc++) {
      int off = (wc * 32 + fc * 16 + l15) * 64 + lk * 16;
      fbh[fc] = *(const bf16x8*)(base + 16384 + off);
      fbl[fc] = *(const bf16x8*)(base + 20480 + off);
    }
    #pragma unroll
    for (int fr = 0; fr < 4; fr++)
      #pragma unroll
      for (int fc = 0; fc < 2; fc++) {
        acc[fr][fc] = __builtin_amdgcn_mfma_f32_16x16x32_bf16(
            fah[fr], fbh[fc], acc[fr][fc], 0, 0, 0);
        acc[fr][fc] = __builtin_amdgcn_mfma_f32_16x16x32_bf16(
            fah[fr], fbl[fc], acc[fr][fc], 0, 0, 0);
        acc[fr][fc] = __builtin_amdgcn_mfma_f32_16x16x32_bf16(
            fal[fr], fbh[fc], acc[fr][fc], 0, 0, 0);
      }
  };

  // r3's exact pipeline: stage-next, compute-current, __syncthreads (the
  // vmcnt(0) drain is covered by the co-resident block — m97 mechanism).
  stage(0, 0);
  __syncthreads();
  int buf = 0;
  for (int kt = 0; kt < NN / 32; kt++) {
    if (kt + 1 < NN / 32) stage(buf ^ 1, kt + 1);
    compute(buf);
    __syncthreads();
    buf ^= 1;
  }

  fused_step_epilogue<4, 2>(acc, b, m0 + wr * 64, c0 + wc * 32,
                            l15, lk, xhc, xlc, xhn, xln, yt, omega, gamma,
                            outbase, qoff, (*flagp != 0));
}

// ---------------------------------------------------------------------------
// FALLBACK (small workspace): round-3 double-buffered 4-batch gemm (916 µs
// path). Grid (4,32,4) = 512 blocks, 2 blocks/CU.
// ---------------------------------------------------------------------------
__global__ __launch_bounds__(256, 2) void gemm_fused_db(
    const u16* __restrict__ Khi, const u16* __restrict__ Klo,
    const u16* __restrict__ xhc, const u16* __restrict__ xlc,
    u16* __restrict__ xhn, u16* __restrict__ xln,
    const float* __restrict__ yt, const void* __restrict__ omega,
    const void* __restrict__ gamma, void* __restrict__ outbase, size_t qoff,
    const int* __restrict__ flagp, int grp)
{
  const int flat = blockIdx.x + 4 * blockIdx.y + 128 * blockIdx.z;
  const int swz  = (flat & 7) * 64 + (flat >> 3);      // 512 % 8 == 0
  const int bx = swz & 3;
  const int by = (swz >> 2) & 31;
  const int bl = swz >> 7;
  const int b  = grp * 4 + bl;
  const int m0 = by * 64;
  const int c0 = bx * 64;

  __shared__ char lds[2][32768];

  const int t    = threadIdx.x;
  const int lane = t & 63;
  const int wid  = t >> 6;
  const int wr   = wid >> 1;
  const int wc   = wid & 1;

  const u16* Ah = Khi + (size_t)bl * NN * NN;
  const u16* Al = Klo + (size_t)bl * NN * NN;
  const u16* Bh = xhc + (size_t)b * CC * NN;
  const u16* Bl = xlc + (size_t)b * CC * NN;

  const int tr   = t >> 3;
  const int phys = (t & 7) ^ (tr & 7);
  const size_t aoff = (size_t)(m0 + tr) * NN + phys * 8;
  const size_t boff = (size_t)(c0 + tr) * NN + phys * 8;
  const int dst = wid * 1024;

  f32x4 acc[2][2];
  const f32x4 zero4 = {0.f, 0.f, 0.f, 0.f};
  #pragma unroll
  for (int i = 0; i < 2; i++)
    #pragma unroll
    for (int j = 0; j < 2; j++) acc[i][j] = zero4;

  auto stage = [&](int bufi, int kt) {
    char* base = &lds[bufi][0];
    const int k0 = kt * 64;
    #pragma unroll
    for (int i = 0; i < 2; i++) {
      gload16(Ah + aoff + (size_t)i * (32 * NN) + k0, base +         i * 4096 + dst);
      gload16(Al + aoff + (size_t)i * (32 * NN) + k0, base +  8192 + i * 4096 + dst);
      gload16(Bh + boff + (size_t)i * (32 * NN) + k0, base + 16384 + i * 4096 + dst);
      gload16(Bl + boff + (size_t)i * (32 * NN) + k0, base + 24576 + i * 4096 + dst);
    }
  };

  const int l15 = lane & 15;
  const int lk  = lane >> 4;

  auto compute = [&](int bufi) {
    const char* base = &lds[bufi][0];
    #pragma unroll
    for (int ks = 0; ks < 2; ks++) {
      const int cl = ks * 4 + lk;
      bf16x8 fah[2], fal[2], fbh[2], fbl[2];
      #pragma unroll
      for (int fr = 0; fr < 2; fr++) {
        int r   = wr * 32 + fr * 16 + l15;
        int off = r * 128 + ((cl ^ (r & 7)) << 4);
        fah[fr] = *(const bf16x8*)(base + off);
        fal[fr] = *(const bf16x8*)(base + 8192 + off);
      }
      #pragma unroll
      for (int fc = 0; fc < 2; fc++) {
        int r   = wc * 32 + fc * 16 + l15;
        int off = r * 128 + ((cl ^ (r & 7)) << 4);
        fbh[fc] = *(const bf16x8*)(base + 16384 + off);
        fbl[fc] = *(const bf16x8*)(base + 24576 + off);
      }
      #pragma unroll
      for (int fr = 0; fr < 2; fr++)
        #pragma unroll
        for (int fc = 0; fc < 2; fc++) {
          acc[fr][fc] = __builtin_amdgcn_mfma_f32_16x16x32_bf16(
              fah[fr], fbh[fc], acc[fr][fc], 0, 0, 0);
          acc[fr][fc] = __builtin_amdgcn_mfma_f32_16x16x32_bf16(
              fah[fr], fbl[fc], acc[fr][fc], 0, 0, 0);
          acc[fr][fc] = __builtin_amdgcn_mfma_f32_16x16x32_bf16(
              fal[fr], fbh[fc], acc[fr][fc], 0, 0, 0);
        }
    }
  };

  stage(0, 0);
  __syncthreads();
  int buf = 0;
  for (int kt = 0; kt < NN / 64; kt++) {
    if (kt + 1 < NN / 64) stage(buf ^ 1, kt + 1);
    compute(buf);
    __syncthreads();
    buf ^= 1;
  }

  fused_step_epilogue<2, 2>(acc, b, m0 + wr * 32, c0 + wc * 32,
                            l15, lk, xhc, xlc, xhn, xln, yt, omega, gamma,
                            outbase, qoff, (*flagp != 0));
}

// ---------------------------------------------------------------------------
extern "C" void kernel_launch(void* const* d_in, const int* in_sizes, int n_in,
                              void* d_out, int out_size, void* d_ws, size_t ws_size,
                              hipStream_t stream) {
  const void* x     = d_in[0];
  const void* y     = d_in[1];
  const void* sc    = d_in[2];
  const void* U     = d_in[3];
  const void* omega = d_in[4];
  const void* gw    = d_in[5];
  const void* gb    = d_in[6];
  const void* gamma = d_in[7];
  // d_in[8] = Q (int32) — fixed at 8 by the problem setup.
  char* ws = (char*)d_ws;

  const size_t BNC = (size_t)BB * NN * CC;               // 4,194,304
  const bool big = ws_size >= 184600000ull;              // 8-batch layout fits

  if (big) {
    u16*   Khi  = (u16*)(ws);                            // 67,108,864 B
    u16*   Klo  = (u16*)(ws + 67108864);                 // 67,108,864 B
    float* yt   = (float*)(ws + 134217728);              // 16,777,216 B
    u16*   xAh  = (u16*)(ws + 150994944);                //  8,388,608 B
    u16*   xAl  = (u16*)(ws + 159383552);                //  8,388,608 B
    u16*   xBh  = (u16*)(ws + 167772160);                //  8,388,608 B
    u16*   xBl  = (u16*)(ws + 176160768);                //  8,388,608 B
    float* murs = (float*)(ws + 184549376);              //  4 KB
    int*   flag = (int*)  (ws + 184553472);              //  4 B
    u16* xh[2] = { xAh, xBh };
    u16* xl[2] = { xAl, xBl };

    detect_kernel<<<dim3(1), dim3(256), 0, stream>>>((const u16*)sc, flag);
    gn_stats_kernel<<<dim3(512), dim3(256), 0, stream>>>(y, murs, flag);
    y_tf_kernel<<<dim3(32, 8), dim3(64, 4), 0, stream>>>(y, murs, gw, gb, yt, flag);
    x_init_kernel<<<dim3(32, 8), dim3(64, 4), 0, stream>>>(x, xAh, xAl, flag);
    build_k_kernel<<<dim3(64, 64, 8), dim3(32, 8), 0, stream>>>(
        sc, U, Khi, Klo, flag, 0);
    for (int q = 0; q < QQ; q++) {
      const int cur = q & 1, nxt = cur ^ 1;
      gemm_fused_r9<<<dim3(4, 16, 8), dim3(256), 0, stream>>>(
          Khi, Klo, xh[cur], xl[cur], xh[nxt], xl[nxt],
          yt, omega, gamma, d_out, (size_t)q * BNC, flag);
    }
  } else {
    // fallback: round-3 layout (~117.4 MB) and path
    u16*   Khi  = (u16*)(ws);                            // 33,554,432 B (4 slots)
    u16*   Klo  = (u16*)(ws + 33554432);                 // 33,554,432 B
    float* yt   = (float*)(ws + 67108864);               // 16,777,216 B
    u16*   xAh  = (u16*)(ws + 83886080);                 //  8,388,608 B
    u16*   xAl  = (u16*)(ws + 92274688);                 //  8,388,608 B
    u16*   xBh  = (u16*)(ws + 100663296);                //  8,388,608 B
    u16*   xBl  = (u16*)(ws + 109051904);                //  8,388,608 B
    float* murs = (float*)(ws + 117440512);              //  4 KB
    int*   flag = (int*)  (ws + 117444608);              //  4 B
    u16* xh[2] = { xAh, xBh };
    u16* xl[2] = { xAl, xBl };

    detect_kernel<<<dim3(1), dim3(256), 0, stream>>>((const u16*)sc, flag);
    gn_stats_kernel<<<dim3(512), dim3(256), 0, stream>>>(y, murs, flag);
    y_tf_kernel<<<dim3(32, 8), dim3(64, 4), 0, stream>>>(y, murs, gw, gb, yt, flag);
    x_init_kernel<<<dim3(32, 8), dim3(64, 4), 0, stream>>>(x, xAh, xAl, flag);
    for (int grp = 0; grp < 2; grp++) {
      build_k_kernel<<<dim3(64, 64, 4), dim3(32, 8), 0, stream>>>(
          sc, U, Khi, Klo, flag, grp * 4);
      for (int q = 0; q < QQ; q++) {
        const int cur = q & 1, nxt = cur ^ 1;
        gemm_fused_db<<<dim3(4, 32, 4), dim3(256), 0, stream>>>(
            Khi, Klo, xh[cur], xl[cur], xh[nxt], xl[nxt],
            yt, omega, gamma, d_out, (size_t)q * BNC, flag, grp);
      }
    }
  }
}

// Round 10
// 854.359 us; speedup vs baseline: 1.1083x; 1.1083x over previous
//
#include <hip/hip_runtime.h>
#include <hip/hip_bf16.h>

// Problem constants (B, N, C fixed by reference)
#define BB 8
#define NN 2048
#define CC 256
#define GG 64        // C / NGRP groups of 4 channels
#define QQ 8

typedef unsigned short u16;
typedef __attribute__((ext_vector_type(8))) short bf16x8;   // 8 bf16 (4 VGPRs)
typedef __attribute__((ext_vector_type(4))) float f32x4;    // MFMA accumulator

static __device__ __forceinline__ float b2f(u16 u) {
  union { unsigned int i; float f; } cv; cv.i = ((unsigned int)u) << 16; return cv.f;
}
static __device__ __forceinline__ u16 f2b(float f) {
  union { __hip_bfloat16 h; u16 u; } cv; cv.h = __float2bfloat16(f); return cv.u;
}
// dtype-flexible scalar load: flag ? float32 : bf16
static __device__ __forceinline__ float ldin(const void* p, size_t i, bool f32) {
  return f32 ? ((const float*)p)[i] : b2f(((const u16*)p)[i]);
}
// 4 consecutive elements as float4 (dtype-flexible)
static __device__ __forceinline__ float4 ldin4(const void* p, size_t i, bool f32) {
  if (f32) return *(const float4*)((const float*)p + i);
  ushort4 u = *(const ushort4*)((const u16*)p + i);
  return make_float4(b2f(u.x), b2f(u.y), b2f(u.z), b2f(u.w));
}
// async global->LDS, 16B per lane; LDS dest = wave-uniform base + lane*16
static __device__ __forceinline__ void gload16(const void* g, void* l) {
  __builtin_amdgcn_global_load_lds(
      (const __attribute__((address_space(1))) void*)g,
      (__attribute__((address_space(3))) void*)l, 16, 0, 0);
}

// ---------------------------------------------------------------------------
// dtype detection (bf16 vs f32 inputs)
// ---------------------------------------------------------------------------
__global__ __launch_bounds__(256) void detect_kernel(const u16* __restrict__ sc,
                                                     int* __restrict__ flag)
{
  __shared__ int sh;
  if (threadIdx.x == 0) sh = 0;
  __syncthreads();
  int cnt = 0;
  for (int i = threadIdx.x; i < 2048; i += 256) {
    u16 w = sc[2 * i];
    int e = (w >> 7) & 0xFF;
    if (e >= 100 && e <= 130) cnt++;
  }
  atomicAdd(&sh, cnt);
  __syncthreads();
  if (threadIdx.x == 0) *flag = (sh < 1024) ? 1 : 0;   // 1 => float32 inputs
}

// ---------------------------------------------------------------------------
// K[bl,i,j] = 0.5*(sc[b,i,j]+sc[b,j,i]) * sigmoid(dot(U[i],U[j]))
// Batch-parallel: grid (64,64,nbat), z = batch; sigmoid recomputed per batch
// (VALU idle anyway) for 8x memory-level parallelism. Lower triangle exits.
// ---------------------------------------------------------------------------
__global__ __launch_bounds__(256) void build_k_kernel(
    const void* __restrict__ sc, const void* __restrict__ U,
    u16* __restrict__ Khi, u16* __restrict__ Klo,
    const int* __restrict__ flagp, int b0)
{
  const int i0 = blockIdx.y * 32;
  const int j0 = blockIdx.x * 32;
  if (j0 < i0) return;
  const bool f32 = (*flagp != 0);
  const int bl = blockIdx.z;
  const int b  = b0 + bl;
  const int tx = threadIdx.x;   // 0..31
  const int ty = threadIdx.y;   // 0..7
  const int t  = ty * 32 + tx;
  const int rr = t >> 3;        // row 0..31
  const int cq = t & 7;         // col quad 0..7 (cols 4cq..4cq+3)

  __shared__ float Ui[32][17];
  __shared__ float Uj[32][17];
  __shared__ float As[32][33];   // As[a][c] = sigmoid(dot(U[i0+a], U[j0+c]))
  __shared__ float t1[32][33];   // t1[a][c] = sc[b, i0+a, j0+c]
  __shared__ float t2[32][33];   // t2[a][c] = sc[b, j0+a, i0+c]

  for (int s = t; s < 512; s += 256) {
    int r2 = s >> 4, kk = s & 15;
    Ui[r2][kk] = ldin(U, (size_t)(i0 + r2) * 16 + kk, f32);
    Uj[r2][kk] = ldin(U, (size_t)(j0 + r2) * 16 + kk, f32);
  }
  const size_t scb = (size_t)b * NN * NN;
  float4 va = ldin4(sc, scb + (size_t)(i0 + rr) * NN + j0 + 4 * cq, f32);
  float4 vb = ldin4(sc, scb + (size_t)(j0 + rr) * NN + i0 + 4 * cq, f32);
  __syncthreads();
  for (int ii = ty; ii < 32; ii += 8) {
    float dot = 0.f;
    #pragma unroll
    for (int k = 0; k < 16; k++) dot += Ui[ii][k] * Uj[tx][k];
    As[ii][tx] = 1.0f / (1.0f + expf(-dot));
  }
  t1[rr][4*cq+0] = va.x; t1[rr][4*cq+1] = va.y;
  t1[rr][4*cq+2] = va.z; t1[rr][4*cq+3] = va.w;
  t2[rr][4*cq+0] = vb.x; t2[rr][4*cq+1] = vb.y;
  t2[rr][4*cq+2] = vb.z; t2[rr][4*cq+3] = vb.w;
  __syncthreads();

  const size_t kfb = (size_t)bl * NN * NN;
  ushort4 h4, l4;
  #pragma unroll
  for (int k = 0; k < 4; k++) {
    int col = 4 * cq + k;
    float kv = 0.5f * (t1[rr][col] + t2[col][rr]) * As[rr][col];
    u16 h = f2b(kv);
    ((u16*)&h4)[k] = h;
    ((u16*)&l4)[k] = f2b(kv - b2f(h));
  }
  size_t o = kfb + (size_t)(i0 + rr) * NN + j0 + 4 * cq;
  *(ushort4*)(Khi + o) = h4;
  *(ushort4*)(Klo + o) = l4;
  if (i0 != j0) {
    #pragma unroll
    for (int k = 0; k < 4; k++) {
      int col = 4 * cq + k;
      float kv = 0.5f * (t2[rr][col] + t1[col][rr]) * As[col][rr];
      u16 h = f2b(kv);
      ((u16*)&h4)[k] = h;
      ((u16*)&l4)[k] = f2b(kv - b2f(h));
    }
    size_t o2 = kfb + (size_t)(j0 + rr) * NN + i0 + 4 * cq;
    *(ushort4*)(Khi + o2) = h4;
    *(ushort4*)(Klo + o2) = l4;
  }
}

// ---------------------------------------------------------------------------
// GroupNorm stats over y[b, 4g:4g+4, :]  (8192 elems per (b,g))
// ---------------------------------------------------------------------------
__global__ __launch_bounds__(256) void gn_stats_kernel(
    const void* __restrict__ y, float* __restrict__ murs,
    const int* __restrict__ flagp)
{
  const bool f32 = (*flagp != 0);
  const int bg = blockIdx.x;                    // b*64 + g
  float s = 0.f, ss = 0.f;
  if (f32) {
    const float* base = (const float*)y + (size_t)bg * 4 * NN;
    for (int i = threadIdx.x; i < 2048; i += 256) {
      float4 v = *(const float4*)(base + (size_t)i * 4);
      s  += v.x + v.y + v.z + v.w;
      ss += v.x*v.x + v.y*v.y + v.z*v.z + v.w*v.w;
    }
  } else {
    const u16* base = (const u16*)y + (size_t)bg * 4 * NN;
    for (int i = threadIdx.x; i < 2048; i += 256) {
      ushort4 v = *(const ushort4*)(base + (size_t)i * 4);
      float f0 = b2f(v.x), f1 = b2f(v.y), f2 = b2f(v.z), f3 = b2f(v.w);
      s  += f0 + f1 + f2 + f3;
      ss += f0*f0 + f1*f1 + f2*f2 + f3*f3;
    }
  }
  #pragma unroll
  for (int off = 32; off > 0; off >>= 1) {
    s  += __shfl_down(s, off, 64);
    ss += __shfl_down(ss, off, 64);
  }
  __shared__ float sh[8];
  const int w = threadIdx.x >> 6, ln = threadIdx.x & 63;
  if (ln == 0) { sh[w * 2] = s; sh[w * 2 + 1] = ss; }
  __syncthreads();
  if (threadIdx.x == 0) {
    float S  = sh[0] + sh[2] + sh[4] + sh[6];
    float SS = sh[1] + sh[3] + sh[5] + sh[7];
    float mu  = S / 8192.0f;
    float var = SS / 8192.0f - mu * mu;
    murs[bg * 2]     = mu;
    murs[bg * 2 + 1] = 1.0f / sqrtf(fmaxf(var, 0.f) + 1e-5f);
  }
}

// ---------------------------------------------------------------------------
// y_t[b,n,c] = sphere( GN(y)[b,c,n] * w + bias ) -> f32 [b][n][c]
// ---------------------------------------------------------------------------
__global__ __launch_bounds__(256) void y_tf_kernel(
    const void* __restrict__ y, const float* __restrict__ murs,
    const void* __restrict__ gw, const void* __restrict__ gb,
    float* __restrict__ yt, const int* __restrict__ flagp)
{
  const bool f32 = (*flagp != 0);
  const int b = blockIdx.y;
  const int n = blockIdx.x * 64 + threadIdx.x;
  for (int g = threadIdx.y; g < GG; g += 4) {
    float mu = murs[(b * GG + g) * 2];
    float rs = murs[(b * GG + g) * 2 + 1];
    float v[4];
    #pragma unroll
    for (int k = 0; k < 4; k++) {
      int c = 4 * g + k;
      float val = (ldin(y, ((size_t)b * CC + c) * NN + n, f32) - mu) * rs;
      v[k] = val * ldin(gw, c, f32) + ldin(gb, c, f32);
    }
    float n2 = v[0]*v[0] + v[1]*v[1] + v[2]*v[2] + v[3]*v[3];
    float scl = 1.0f / sqrtf(fmaxf(n2, 1e-6f));
    float4 o; o.x = v[0]*scl; o.y = v[1]*scl; o.z = v[2]*scl; o.w = v[3]*scl;
    *(float4*)(yt + ((size_t)b * NN + n) * CC + 4 * g) = o;
  }
}

// ---------------------------------------------------------------------------
// x init: sphere-normalize x -> bf16 hi/lo transposed state xT[b][c][n]
// ---------------------------------------------------------------------------
__global__ __launch_bounds__(256) void x_init_kernel(
    const void* __restrict__ x, u16* __restrict__ xTh, u16* __restrict__ xTl,
    const int* __restrict__ flagp)
{
  const bool f32 = (*flagp != 0);
  const int b = blockIdx.y;
  const int n = blockIdx.x * 64 + threadIdx.x;
  for (int g = threadIdx.y; g < GG; g += 4) {
    size_t idx = ((size_t)b * NN + n) * CC + 4 * g;
    float v[4];
    if (f32) {
      float4 u4 = *(const float4*)((const float*)x + idx);
      v[0] = u4.x; v[1] = u4.y; v[2] = u4.z; v[3] = u4.w;
    } else {
      ushort4 u = *(const ushort4*)((const u16*)x + idx);
      v[0] = b2f(u.x); v[1] = b2f(u.y); v[2] = b2f(u.z); v[3] = b2f(u.w);
    }
    float n2 = v[0]*v[0] + v[1]*v[1] + v[2]*v[2] + v[3]*v[3];
    float scl = 1.0f / sqrtf(fmaxf(n2, 1e-6f));
    size_t xb = ((size_t)b * CC + 4 * g) * NN + n;
    #pragma unroll
    for (int k = 0; k < 4; k++) {
      float xv = v[k] * scl;
      u16 h = f2b(xv);
      xTh[xb + (size_t)k * NN] = h;
      xTl[xb + (size_t)k * NN] = f2b(xv - b2f(h));
    }
  }
}

// ===========================================================================
// Shared fused-step epilogue. Rows: rb + fr*16 + lk*4 + r. Cols: cb + fc*16
// + l15. The 4-channel group spans lanes differing in l15 bits 0..1.
// d_out stores nontemporal (written once, never read).
// ===========================================================================
template<int NFR, int NFC>
static __device__ __forceinline__ void fused_step_epilogue(
    f32x4 (&acc)[NFR][NFC], int b, int rb, int cb, int l15, int lk,
    const u16* __restrict__ xhc, const u16* __restrict__ xlc,
    u16* __restrict__ xhn, u16* __restrict__ xln,
    const float* __restrict__ yt, const void* __restrict__ omega,
    const void* __restrict__ gamma, void* __restrict__ outbase, size_t qoff,
    bool f32)
{
  const float gm = ldin(gamma, 0, f32);
  #pragma unroll
  for (int fr = 0; fr < NFR; fr++) {
    const int rbase = rb + fr * 16 + lk * 4;
    #pragma unroll
    for (int fc = 0; fc < NFC; fc++) {
      const int c = cb + fc * 16 + l15;
      const size_t xoff = ((size_t)b * CC + c) * NN + rbase;
      ushort4 xh4 = *(const ushort4*)(xhc + xoff);
      ushort4 xl4 = *(const ushort4*)(xlc + xoff);
      float xcv[4] = { b2f(xh4.x) + b2f(xl4.x), b2f(xh4.y) + b2f(xl4.y),
                       b2f(xh4.z) + b2f(xl4.z), b2f(xh4.w) + b2f(xl4.w) };
      float om   = fabsf(ldin(omega, c >> 1, f32));
      float omsg = (c & 1) ? -om : om;
      float xn[4];
      #pragma unroll
      for (int r = 0; r < 4; r++) {
        const int n = rbase + r;
        float f = acc[fr][fc][r] + yt[((size_t)b * NN + n) * CC + c];
        float s = xcv[r] * f;
        s += __shfl_xor(s, 1);
        s += __shfl_xor(s, 2);
        float xp = __shfl_xor(xcv[r], 1);       // pair partner channel c^1
        float d  = omsg * xp + (f - s * xcv[r]);
        float v  = xcv[r] + gm * d;
        float n2 = v * v;
        n2 += __shfl_xor(n2, 1);
        n2 += __shfl_xor(n2, 2);
        float scl = 1.0f / sqrtf(fmaxf(n2, 1e-6f));
        xn[r] = v * scl;
        const size_t oidx = qoff + ((size_t)b * NN + n) * CC + c;
        if (f32) __builtin_nontemporal_store(xn[r], (float*)outbase + oidx);
        else     __builtin_nontemporal_store(f2b(xn[r]), (u16*)outbase + oidx);
      }
      ushort4 nh, nl;
      #pragma unroll
      for (int r = 0; r < 4; r++) {
        u16 h = f2b(xn[r]);
        ((u16*)&nh)[r] = h;
        ((u16*)&nl)[r] = f2b(xn[r] - b2f(h));
      }
      *(ushort4*)(xhn + xoff) = nh;
      *(ushort4*)(xln + xoff) = nl;
    }
  }
}

// ---------------------------------------------------------------------------
// Round-10 gemm: r7's exact 128x128 geometry (best measured: 907 us total,
// verified swizzle, BK=64, 8 waves 2x(2x2), dbuf 2x64KB, 1 blk/CU) with the
// PURE compiler-scheduled sync loop of r3 (best measured per-byte LDS
// efficiency, 50 B/cyc): stage(next); compute(cur); __syncthreads(). No
// inline asm, no sched_barrier pins (m141), no setprio. The stage for kt+1
// is issued BEFORE compute(kt), so its DMA has the whole ~3K-cyc compute to
// land before the barrier's vmcnt(0) — the drain is not exposed (this is
// why r3 == r5 and counted-vmcnt never helped). Clean A/B vs r7's asm
// pipeline at identical geometry.
// Grid (2,16,8) = 256 blocks = 1/CU, 512 thr.
// ---------------------------------------------------------------------------
__global__ __launch_bounds__(512, 2) void gemm_fused_p10(
    const u16* __restrict__ Khi, const u16* __restrict__ Klo,
    const u16* __restrict__ xhc, const u16* __restrict__ xlc,
    u16* __restrict__ xhn, u16* __restrict__ xln,
    const float* __restrict__ yt, const void* __restrict__ omega,
    const void* __restrict__ gamma, void* __restrict__ outbase, size_t qoff,
    const int* __restrict__ flagp)
{
  const int flat = blockIdx.x + 2 * blockIdx.y + 32 * blockIdx.z;  // 0..255
  const int swz  = (flat & 7) * 32 + (flat >> 3);   // 256 % 8 == 0: bijective
  const int bx = swz & 1;
  const int by = (swz >> 1) & 15;
  const int b  = swz >> 5;                          // batch 0..7 (= K slot)
  const int m0 = by * 128;
  const int c0 = bx * 128;

  // per buffer: Ah[128][64] @0 (16KB), Al @16384, Bh @32768, Bl @49152
  __shared__ char lds[2][65536];

  const int t    = threadIdx.x;
  const int lane = t & 63;
  const int wid  = t >> 6;      // 0..7
  const int ng   = wid >> 2;    // N-half group 0..1
  const int wr   = (wid >> 1) & 1;   // wave row in group (64 rows each)
  const int wc   = wid & 1;          // wave col in group (32 cols each)

  const u16* Ah = Khi + (size_t)b * NN * NN;
  const u16* Al = Klo + (size_t)b * NN * NN;
  const u16* Bh = xhc + (size_t)b * CC * NN;
  const u16* Bl = xlc + (size_t)b * CC * NN;

  // staging: region = 128 rows x 128B (8 chunks). thread t covers rows tr,
  // tr+64; slot = t&7; source chunk = slot ^ (row&7) (row&7 same for both i).
  const int tr   = t >> 3;                       // 0..63
  const int phys = (t & 7) ^ (tr & 7);
  const size_t aoff = (size_t)(m0 + tr) * NN + phys * 8;
  const size_t boff = (size_t)(c0 + tr) * NN + phys * 8;
  const int dst = wid * 1024;                    // + lane*16 implicit in HW

  f32x4 acc[4][2];
  const f32x4 zero4 = {0.f, 0.f, 0.f, 0.f};
  #pragma unroll
  for (int i = 0; i < 4; i++)
    #pragma unroll
    for (int j = 0; j < 2; j++) acc[i][j] = zero4;

  auto stage = [&](int bufi, int kt) {           // 8 vmem ops per thread
    char* base = &lds[bufi][0];
    const int k0 = kt * 64;
    #pragma unroll
    for (int i = 0; i < 2; i++) {
      gload16(Ah + aoff + (size_t)i * (64 * NN) + k0, base +         i * 8192 + dst);
      gload16(Al + aoff + (size_t)i * (64 * NN) + k0, base + 16384 + i * 8192 + dst);
      gload16(Bh + boff + (size_t)i * (64 * NN) + k0, base + 32768 + i * 8192 + dst);
      gload16(Bl + boff + (size_t)i * (64 * NN) + k0, base + 49152 + i * 8192 + dst);
    }
  };

  const int l15 = lane & 15;
  const int lk  = lane >> 4;     // 0..3

  auto compute = [&](int bufi) {
    const char* base = &lds[bufi][0];
    #pragma unroll
    for (int ks = 0; ks < 2; ks++) {             // two K=32 MFMA steps per tile
      const int cl = ks * 4 + lk;                // logical 16B chunk (k/8)
      bf16x8 fah[4], fal[4], fbh[2], fbl[2];
      #pragma unroll
      for (int fr = 0; fr < 4; fr++) {
        int r   = wr * 64 + fr * 16 + l15;
        int off = r * 128 + ((cl ^ (r & 7)) << 4);
        fah[fr] = *(const bf16x8*)(base + off);
        fal[fr] = *(const bf16x8*)(base + 16384 + off);
      }
      #pragma unroll
      for (int fc = 0; fc < 2; fc++) {
        int r   = ng * 64 + wc * 32 + fc * 16 + l15;
        int off = r * 128 + ((cl ^ (r & 7)) << 4);
        fbh[fc] = *(const bf16x8*)(base + 32768 + off);
        fbl[fc] = *(const bf16x8*)(base + 49152 + off);
      }
      #pragma unroll
      for (int fr = 0; fr < 4; fr++)
        #pragma unroll
        for (int fc = 0; fc < 2; fc++) {
          acc[fr][fc] = __builtin_amdgcn_mfma_f32_16x16x32_bf16(
              fah[fr], fbh[fc], acc[fr][fc], 0, 0, 0);
          acc[fr][fc] = __builtin_amdgcn_mfma_f32_16x16x32_bf16(
              fah[fr], fbl[fc], acc[fr][fc], 0, 0, 0);
          acc[fr][fc] = __builtin_amdgcn_mfma_f32_16x16x32_bf16(
              fal[fr], fbh[fc], acc[fr][fc], 0, 0, 0);
        }
    }
  };

  // pure compiler-scheduled dbuf (r3's loop, r7's geometry)
  stage(0, 0);
  __syncthreads();
  int buf = 0;
  for (int kt = 0; kt < NN / 64; kt++) {
    if (kt + 1 < NN / 64) stage(buf ^ 1, kt + 1);
    compute(buf);
    __syncthreads();
    buf ^= 1;
  }

  fused_step_epilogue<4, 2>(acc, b, m0 + wr * 64, c0 + ng * 64 + wc * 32,
                            l15, lk, xhc, xlc, xhn, xln, yt, omega, gamma,
                            outbase, qoff, (*flagp != 0));
}

// ---------------------------------------------------------------------------
// FALLBACK (small workspace): round-3 double-buffered 4-batch gemm (916 µs
// path). Grid (4,32,4) = 512 blocks, 2 blocks/CU.
// ---------------------------------------------------------------------------
__global__ __launch_bounds__(256, 2) void gemm_fused_db(
    const u16* __restrict__ Khi, const u16* __restrict__ Klo,
    const u16* __restrict__ xhc, const u16* __restrict__ xlc,
    u16* __restrict__ xhn, u16* __restrict__ xln,
    const float* __restrict__ yt, const void* __restrict__ omega,
    const void* __restrict__ gamma, void* __restrict__ outbase, size_t qoff,
    const int* __restrict__ flagp, int grp)
{
  const int flat = blockIdx.x + 4 * blockIdx.y + 128 * blockIdx.z;
  const int swz  = (flat & 7) * 64 + (flat >> 3);      // 512 % 8 == 0
  const int bx = swz & 3;
  const int by = (swz >> 2) & 31;
  const int bl = swz >> 7;
  const int b  = grp * 4 + bl;
  const int m0 = by * 64;
  const int c0 = bx * 64;

  __shared__ char lds[2][32768];

  const int t    = threadIdx.x;
  const int lane = t & 63;
  const int wid  = t >> 6;
  const int wr   = wid >> 1;
  const int wc   = wid & 1;

  const u16* Ah = Khi + (size_t)bl * NN * NN;
  const u16* Al = Klo + (size_t)bl * NN * NN;
  const u16* Bh = xhc + (size_t)b * CC * NN;
  const u16* Bl = xlc + (size_t)b * CC * NN;

  const int tr   = t >> 3;
  const int phys = (t & 7) ^ (tr & 7);
  const size_t aoff = (size_t)(m0 + tr) * NN + phys * 8;
  const size_t boff = (size_t)(c0 + tr) * NN + phys * 8;
  const int dst = wid * 1024;

  f32x4 acc[2][2];
  const f32x4 zero4 = {0.f, 0.f, 0.f, 0.f};
  #pragma unroll
  for (int i = 0; i < 2; i++)
    #pragma unroll
    for (int j = 0; j < 2; j++) acc[i][j] = zero4;

  auto stage = [&](int bufi, int kt) {
    char* base = &lds[bufi][0];
    const int k0 = kt * 64;
    #pragma unroll
    for (int i = 0; i < 2; i++) {
      gload16(Ah + aoff + (size_t)i * (32 * NN) + k0, base +         i * 4096 + dst);
      gload16(Al + aoff + (size_t)i * (32 * NN) + k0, base +  8192 + i * 4096 + dst);
      gload16(Bh + boff + (size_t)i * (32 * NN) + k0, base + 16384 + i * 4096 + dst);
      gload16(Bl + boff + (size_t)i * (32 * NN) + k0, base + 24576 + i * 4096 + dst);
    }
  };

  const int l15 = lane & 15;
  const int lk  = lane >> 4;

  auto compute = [&](int bufi) {
    const char* base = &lds[bufi][0];
    #pragma unroll
    for (int ks = 0; ks < 2; ks++) {
      const int cl = ks * 4 + lk;
      bf16x8 fah[2], fal[2], fbh[2], fbl[2];
      #pragma unroll
      for (int fr = 0; fr < 2; fr++) {
        int r   = wr * 32 + fr * 16 + l15;
        int off = r * 128 + ((cl ^ (r & 7)) << 4);
        fah[fr] = *(const bf16x8*)(base + off);
        fal[fr] = *(const bf16x8*)(base + 8192 + off);
      }
      #pragma unroll
      for (int fc = 0; fc < 2; fc++) {
        int r   = wc * 32 + fc * 16 + l15;
        int off = r * 128 + ((cl ^ (r & 7)) << 4);
        fbh[fc] = *(const bf16x8*)(base + 16384 + off);
        fbl[fc] = *(const bf16x8*)(base + 24576 + off);
      }
      #pragma unroll
      for (int fr = 0; fr < 2; fr++)
        #pragma unroll
        for (int fc = 0; fc < 2; fc++) {
          acc[fr][fc] = __builtin_amdgcn_mfma_f32_16x16x32_bf16(
              fah[fr], fbh[fc], acc[fr][fc], 0, 0, 0);
          acc[fr][fc] = __builtin_amdgcn_mfma_f32_16x16x32_bf16(
              fah[fr], fbl[fc], acc[fr][fc], 0, 0, 0);
          acc[fr][fc] = __builtin_amdgcn_mfma_f32_16x16x32_bf16(
              fal[fr], fbh[fc], acc[fr][fc], 0, 0, 0);
        }
    }
  };

  stage(0, 0);
  __syncthreads();
  int buf = 0;
  for (int kt = 0; kt < NN / 64; kt++) {
    if (kt + 1 < NN / 64) stage(buf ^ 1, kt + 1);
    compute(buf);
    __syncthreads();
    buf ^= 1;
  }

  fused_step_epilogue<2, 2>(acc, b, m0 + wr * 32, c0 + wc * 32,
                            l15, lk, xhc, xlc, xhn, xln, yt, omega, gamma,
                            outbase, qoff, (*flagp != 0));
}

// ---------------------------------------------------------------------------
extern "C" void kernel_launch(void* const* d_in, const int* in_sizes, int n_in,
                              void* d_out, int out_size, void* d_ws, size_t ws_size,
                              hipStream_t stream) {
  const void* x     = d_in[0];
  const void* y     = d_in[1];
  const void* sc    = d_in[2];
  const void* U     = d_in[3];
  const void* omega = d_in[4];
  const void* gw    = d_in[5];
  const void* gb    = d_in[6];
  const void* gamma = d_in[7];
  // d_in[8] = Q (int32) — fixed at 8 by the problem setup.
  char* ws = (char*)d_ws;

  const size_t BNC = (size_t)BB * NN * CC;               // 4,194,304
  const bool big = ws_size >= 184600000ull;              // 8-batch layout fits

  if (big) {
    u16*   Khi  = (u16*)(ws);                            // 67,108,864 B
    u16*   Klo  = (u16*)(ws + 67108864);                 // 67,108,864 B
    float* yt   = (float*)(ws + 134217728);              // 16,777,216 B
    u16*   xAh  = (u16*)(ws + 150994944);                //  8,388,608 B
    u16*   xAl  = (u16*)(ws + 159383552);                //  8,388,608 B
    u16*   xBh  = (u16*)(ws + 167772160);                //  8,388,608 B
    u16*   xBl  = (u16*)(ws + 176160768);                //  8,388,608 B
    float* murs = (float*)(ws + 184549376);              //  4 KB
    int*   flag = (int*)  (ws + 184553472);              //  4 B
    u16* xh[2] = { xAh, xBh };
    u16* xl[2] = { xAl, xBl };

    detect_kernel<<<dim3(1), dim3(256), 0, stream>>>((const u16*)sc, flag);
    gn_stats_kernel<<<dim3(512), dim3(256), 0, stream>>>(y, murs, flag);
    y_tf_kernel<<<dim3(32, 8), dim3(64, 4), 0, stream>>>(y, murs, gw, gb, yt, flag);
    x_init_kernel<<<dim3(32, 8), dim3(64, 4), 0, stream>>>(x, xAh, xAl, flag);
    build_k_kernel<<<dim3(64, 64, 8), dim3(32, 8), 0, stream>>>(
        sc, U, Khi, Klo, flag, 0);
    for (int q = 0; q < QQ; q++) {
      const int cur = q & 1, nxt = cur ^ 1;
      gemm_fused_p10<<<dim3(2, 16, 8), dim3(512), 0, stream>>>(
          Khi, Klo, xh[cur], xl[cur], xh[nxt], xl[nxt],
          yt, omega, gamma, d_out, (size_t)q * BNC, flag);
    }
  } else {
    // fallback: round-3 layout (~117.4 MB) and path
    u16*   Khi  = (u16*)(ws);                            // 33,554,432 B (4 slots)
    u16*   Klo  = (u16*)(ws + 33554432);                 // 33,554,432 B
    float* yt   = (float*)(ws + 67108864);               // 16,777,216 B
    u16*   xAh  = (u16*)(ws + 83886080);                 //  8,388,608 B
    u16*   xAl  = (u16*)(ws + 92274688);                 //  8,388,608 B
    u16*   xBh  = (u16*)(ws + 100663296);                //  8,388,608 B
    u16*   xBl  = (u16*)(ws + 109051904);                //  8,388,608 B
    float* murs = (float*)(ws + 117440512);              //  4 KB
    int*   flag = (int*)  (ws + 117444608);              //  4 B
    u16* xh[2] = { xAh, xBh };
    u16* xl[2] = { xAl, xBl };

    detect_kernel<<<dim3(1), dim3(256), 0, stream>>>((const u16*)sc, flag);
    gn_stats_kernel<<<dim3(512), dim3(256), 0, stream>>>(y, murs, flag);
    y_tf_kernel<<<dim3(32, 8), dim3(64, 4), 0, stream>>>(y, murs, gw, gb, yt, flag);
    x_init_kernel<<<dim3(32, 8), dim3(64, 4), 0, stream>>>(x, xAh, xAl, flag);
    for (int grp = 0; grp < 2; grp++) {
      build_k_kernel<<<dim3(64, 64, 4), dim3(32, 8), 0, stream>>>(
          sc, U, Khi, Klo, flag, grp * 4);
      for (int q = 0; q < QQ; q++) {
        const int cur = q & 1, nxt = cur ^ 1;
        gemm_fused_db<<<dim3(4, 32, 4), dim3(256), 0, stream>>>(
            Khi, Klo, xh[cur], xl[cur], xh[nxt], xl[nxt],
            yt, omega, gamma, d_out, (size_t)q * BNC, flag, grp);
      }
    }
  }
}